// Round 5
// baseline (356.110 us; speedup 1.0000x reference)
//
#include <hip/hip_runtime.h>
#include <hip/hip_bf16.h>

typedef short short8 __attribute__((ext_vector_type(8)));
typedef unsigned short ushort8v __attribute__((ext_vector_type(8)));
typedef float f32x4 __attribute__((ext_vector_type(4)));

#define D_DIM 2048
#define KTOT 4096      // x|h concatenated along K
#define M_TOT 8192     // B*S
#define NPACK 4096     // interleaved Bi|Bc rows

// ---------------- helpers ----------------

__device__ __forceinline__ unsigned short f2bf(float f) {
    union { float f; unsigned u; } c; c.f = f;
    unsigned u = c.u;
    u += 0x7fffu + ((u >> 16) & 1u);   // round-to-nearest-even
    return (unsigned short)(u >> 16);
}

__device__ __forceinline__ float fast_tanh(float x) {
    float ax = fabsf(x);
    float ez = __expf(2.0f * fminf(ax, 15.0f));
    float t = (ez - 1.0f) / (ez + 1.0f);
    return copysignf(t, x);
}

#define GLOAD_LDS16(g, l)                                                     \
    __builtin_amdgcn_global_load_lds(                                         \
        (const __attribute__((address_space(1))) void*)(g),                   \
        (__attribute__((address_space(3))) void*)(l), 16, 0, 0)

// ---------------- pack two f32 [R][2048] matrices into bf16 [R][4096] ------

__global__ __launch_bounds__(256)
void pack2(const float* __restrict__ X, const float* __restrict__ H,
           __hip_bfloat16* __restrict__ dst, int total8) {
    int t = blockIdx.x * 256 + threadIdx.x;
    if (t >= total8) return;
    long e0 = (long)t * 8;
    long r  = e0 >> 12;            // / 4096
    int  k  = (int)(e0 & 4095);
    const float* src = (k < D_DIM) ? (X + r * D_DIM + k)
                                   : (H + r * D_DIM + (k - D_DIM));
    float4 v0 = *(const float4*)(src);
    float4 v1 = *(const float4*)(src + 4);
    ushort8v o;
    o[0] = f2bf(v0.x); o[1] = f2bf(v0.y); o[2] = f2bf(v0.z); o[3] = f2bf(v0.w);
    o[4] = f2bf(v1.x); o[5] = f2bf(v1.y); o[6] = f2bf(v1.z); o[7] = f2bf(v1.w);
    *(ushort8v*)(dst + e0) = o;
}

// ---- pack gate weights, Bi/Bc interleaved in 16-row groups ----------------

__global__ __launch_bounds__(256)
void pack_gates(const float* __restrict__ Wi, const float* __restrict__ Ui,
                const float* __restrict__ Wc, const float* __restrict__ Uc,
                __hip_bfloat16* __restrict__ dst) {
    int t = blockIdx.x * 256 + threadIdx.x;    // 4096*512 threads
    const int g = t >> 9;
    const int k = (t & 511) * 8;
    const int w = g & 31;
    const int n = ((g >> 5) << 4) | (w & 15);
    const float* Wm = (w & 16) ? Wc : Wi;
    const float* Um = (w & 16) ? Uc : Ui;
    const float* src = (k < D_DIM) ? (Wm + (size_t)n * D_DIM + k)
                                   : (Um + (size_t)n * D_DIM + (k - D_DIM));
    float4 v0 = *(const float4*)(src);
    float4 v1 = *(const float4*)(src + 4);
    ushort8v o;
    o[0] = f2bf(v0.x); o[1] = f2bf(v0.y); o[2] = f2bf(v0.z); o[3] = f2bf(v0.w);
    o[4] = f2bf(v1.x); o[5] = f2bf(v1.y); o[6] = f2bf(v1.z); o[7] = f2bf(v1.w);
    *(ushort8v*)(dst + (size_t)g * KTOT + k) = o;
}

// ---------------- 8-phase 256x256 fused GEMM, reg-pipelined ----------------
// Same sync ledger as the verified round-4 kernel (fragments prefetched one
// phase ahead; counted lgkmcnt(4/8); vmcnt(2) drains at P1/P3 only). All
// addressing hoisted: 4 per-thread global staging pointers bumped by a
// uniform byte counter, ds_reads from 2 per-thread LDS bases with all
// buffer/khalf/row selection as compile-time immediates (K-loop unrolled 2
// tiles/iter so buffer parity is static).

#define BK 64
#define NT (KTOT / BK)   // 64 K-tiles

__device__ __forceinline__ void mfma16(f32x4 (&acc)[8][4], int mb,
                                       const short8 (&a)[4], const short8 (&b)[4]) {
    #pragma unroll
    for (int m = 0; m < 4; ++m)
        #pragma unroll
        for (int n = 0; n < 4; ++n)
            acc[mb + m][n] = __builtin_amdgcn_mfma_f32_16x16x32_bf16(
                a[m], b[n], acc[mb + m][n], 0, 0, 0);
}

// 4 ds_read_b128 from per-thread base + compile-time immediate
#define READ4(dst, base, IMM)                                                 \
    { _Pragma("unroll")                                                       \
      for (int m_ = 0; m_ < 4; ++m_)                                          \
          dst[m_] = *(const short8*)((base) + (IMM) + m_ * 1024); }

// stage one 256x32 half-tile: 2 global_load_lds per thread, pointer+kb form
#define STAGE2(g0, g1, ldsbase, DIMM, KB)                                     \
    { GLOAD_LDS16((g0) + (KB), (ldsbase) + (DIMM) + dOff);                    \
      GLOAD_LDS16((g1) + (KB), (ldsbase) + (DIMM) + dOff + 1024); }

// one K-tile: 4 phases. CUROFF/NXTOFF in {0,32768} are compile-time.
#define TILE(CUROFF, NXTOFF, PF)                                              \
  {                                                                           \
    /* P1: MFMA aP x bP (kh0 m0-3); read aQ (kh0 m4-7); stage A kh0(t+1) */   \
    READ4(aQ, rdA, (CUROFF) + 4096);                                          \
    if (PF) { STAGE2(gA0, gA1, ldsA, (NXTOFF), kb);                           \
              asm volatile("s_waitcnt vmcnt(2)" ::: "memory"); }              \
    else    { asm volatile("s_waitcnt vmcnt(0)" ::: "memory"); }              \
    __builtin_amdgcn_s_barrier();                                             \
    asm volatile("s_waitcnt lgkmcnt(4)" ::: "memory");                        \
    __builtin_amdgcn_sched_barrier(0);                                        \
    __builtin_amdgcn_s_setprio(1); mfma16(acc, 0, aP, bP);                    \
    __builtin_amdgcn_s_setprio(0);                                            \
    /* P2: MFMA aQ x bP (kh0 m4-7); read aP,bQ (kh1); stage B kh0(t+1) */     \
    READ4(aP, rdA, (CUROFF) + 16384);                                         \
    READ4(bQ, rdB, (CUROFF) + 16384);                                         \
    if (PF) STAGE2(gB0, gB1, ldsB, (NXTOFF), kb);                             \
    __builtin_amdgcn_s_barrier();                                             \
    asm volatile("s_waitcnt lgkmcnt(8)" ::: "memory");                        \
    __builtin_amdgcn_sched_barrier(0);                                        \
    __builtin_amdgcn_s_setprio(1); mfma16(acc, 4, aQ, bP);                    \
    __builtin_amdgcn_s_setprio(0);                                            \
    /* P3: MFMA aP x bQ (kh1 m0-3); read aQ (kh1 m4-7); stage A kh1(t+1) */   \
    READ4(aQ, rdA, (CUROFF) + 16384 + 4096);                                  \
    if (PF) { STAGE2(gA0, gA1, ldsA, (NXTOFF) + 16384, kb + 64);              \
              asm volatile("s_waitcnt vmcnt(2)" ::: "memory"); }              \
    else    { asm volatile("s_waitcnt vmcnt(0)" ::: "memory"); }              \
    __builtin_amdgcn_s_barrier();                                             \
    asm volatile("s_waitcnt lgkmcnt(4)" ::: "memory");                        \
    __builtin_amdgcn_sched_barrier(0);                                        \
    __builtin_amdgcn_s_setprio(1); mfma16(acc, 0, aP, bQ);                    \
    __builtin_amdgcn_s_setprio(0);                                            \
    /* P4: MFMA aQ x bQ (kh1 m4-7); read aP,bP (next kh0); stage B kh1 */     \
    if (PF) { READ4(aP, rdA, (NXTOFF));                                       \
              READ4(bP, rdB, (NXTOFF));                                       \
              STAGE2(gB0, gB1, ldsB, (NXTOFF) + 16384, kb + 64); }            \
    __builtin_amdgcn_s_barrier();                                             \
    if (PF) asm volatile("s_waitcnt lgkmcnt(8)" ::: "memory");                \
    else    asm volatile("s_waitcnt lgkmcnt(0)" ::: "memory");                \
    __builtin_amdgcn_sched_barrier(0);                                        \
    __builtin_amdgcn_s_setprio(1); mfma16(acc, 4, aQ, bQ);                    \
    __builtin_amdgcn_s_setprio(0);                                            \
  }

__global__ __launch_bounds__(512, 2)
void gemm8(const __hip_bfloat16* __restrict__ A,
           const __hip_bfloat16* __restrict__ Bp,
           const float* __restrict__ bWi, const float* __restrict__ bUi,
           const float* __restrict__ bWc, const float* __restrict__ bUc,
           float* __restrict__ Cout) {
    // [buf][khalf][row][32 cols]; buf stride 32768 B, khalf stride 16384 B
    __shared__ __hip_bfloat16 sA[2][2][256][32];
    __shared__ __hip_bfloat16 sB[2][2][256][32];

    const int tid  = threadIdx.x;
    const int wid  = tid >> 6;
    const int lane = tid & 63;

    // XCD swizzle: 512 blocks, 512%8==0 -> bijective
    int bid = blockIdx.x;
    bid = (bid & 7) * 64 + (bid >> 3);
    const int tn = (bid & 15) * 256;   // Bpack row tile (16 tiles)
    const int tm = (bid >> 4) * 256;   // M tile (32 tiles)

    const int wr  = (wid >> 2) * 128;  // wave M offset
    const int wc  = (wid & 3) * 64;    // wave Bpack-row offset
    const int r15 = lane & 15;
    // balanced-quad swizzle: unit p = g ^ ((row>>1)&3); conflict-free b128
    const int uswz16 = (((lane >> 4) ^ ((r15 >> 1) & 3)) * 16);

    // ---- hoisted staging addresses (computed once) ----
    const int Lb0  = wid * 128 + lane;            // 16B-unit index, j=0
    const int row0 = Lb0 >> 2;
    const int u0   = (Lb0 & 3) ^ ((Lb0 >> 3) & 3);   // j=1 swizzle identical
    const char* gA0 = (const char*)(A  + (size_t)(tm + row0) * KTOT) + u0 * 16;
    const char* gA1 = gA0 + (size_t)16 * KTOT * 2;   // j=1 = rows +16
    const char* gB0 = (const char*)(Bp + (size_t)(tn + row0) * KTOT) + u0 * 16;
    const char* gB1 = gB0 + (size_t)16 * KTOT * 2;
    char* ldsA = (char*)sA;
    char* ldsB = (char*)sB;
    const int dOff = Lb0 * 16;                    // LDS dest byte, j=0

    // ---- hoisted ds_read bases ----
    const char* rdA = (const char*)sA + (wr + r15) * 64 + uswz16;
    const char* rdB = (const char*)sB + (wc + r15) * 64 + uswz16;

    f32x4 acc[8][4] = {};
    short8 aP[4], aQ[4], bP[4], bQ[4];

    // ---- prologue: stage tile 0 into buf0, drain kh0, read P1 frags ----
    STAGE2(gA0, gA1, ldsA, 0, 0);
    STAGE2(gB0, gB1, ldsB, 0, 0);
    STAGE2(gA0, gA1, ldsA, 16384, 64);
    STAGE2(gB0, gB1, ldsB, 16384, 64);
    asm volatile("s_waitcnt vmcnt(4)" ::: "memory");
    __builtin_amdgcn_s_barrier();
    READ4(aP, rdA, 0);
    READ4(bP, rdB, 0);

    int kb = 128;   // byte offset of the K-half being staged (tile t+1 kh0)
    #pragma unroll 1
    for (int it = 0; it < 31; ++it) {
        TILE(0, 32768, 1); kb += 128;       // even tile
        TILE(32768, 0, 1); kb += 128;       // odd tile
    }
    TILE(0, 32768, 1); kb += 128;           // t = 62
    TILE(32768, 0, 0);                      // t = 63 (no prefetch, full drain)

    // ---- epilogue: pair (Zi,Zc) fragments -> c = exp(Zi)*tanh(Zc) ----
    const int rg4 = (lane >> 4) * 4;
    #pragma unroll
    for (int q = 0; q < 2; ++q) {
        const int gn = (tn >> 1) + (wc >> 1) + q * 16 + r15;
        const float bi_ = bWi[gn] + bUi[gn];
        const float bc_ = bWc[gn] + bUc[gn];
        #pragma unroll
        for (int m = 0; m < 8; ++m) {
            const int gm = tm + wr + m * 16 + rg4;
            #pragma unroll
            for (int r = 0; r < 4; ++r) {
                const float zi = acc[m][2 * q][r]     + bi_;
                const float zc = acc[m][2 * q + 1][r] + bc_;
                Cout[(size_t)(gm + r) * D_DIM + gn] = __expf(zi) * fast_tanh(zc);
            }
        }
    }
}

// ---------------- last-timestep o-gate: hbuf[b][e] = sig(Zo)*tanh(c) -------

__global__ __launch_bounds__(256)
void last_gate(const float* __restrict__ x, const float* __restrict__ h,
               const float* __restrict__ Wo, const float* __restrict__ bWo,
               const float* __restrict__ Uo, const float* __restrict__ bUo,
               const float* __restrict__ cfull, float* __restrict__ hbuf) {
    const int o    = blockIdx.x * 4 + (threadIdx.x >> 6);
    const int lane = threadIdx.x & 63;
    const int b = o >> 11, e = o & 2047;
    const float* xr = x  + ((size_t)b * D_DIM + (D_DIM - 1)) * D_DIM;
    const float* hr = h  + ((size_t)b * D_DIM + (D_DIM - 1)) * D_DIM;
    const float* wo = Wo + (size_t)e * D_DIM;
    const float* uo = Uo + (size_t)e * D_DIM;
    float s = 0.0f;
    for (int d = lane; d < D_DIM; d += 64)
        s += xr[d] * wo[d] + hr[d] * uo[d];
    #pragma unroll
    for (int off = 32; off; off >>= 1) s += __shfl_down(s, off);
    if (lane == 0) {
        const float zo  = s + bWo[e] + bUo[e];
        const float sig = 1.0f / (1.0f + __expf(-zo));
        const float cv  = cfull[((size_t)b * D_DIM + (D_DIM - 1)) * D_DIM + e];
        hbuf[o] = sig * fast_tanh(cv);
    }
}

// ---------------- final projection: out[b][p] = hbuf[b] . Wp[p] + bp[p] ----

__global__ __launch_bounds__(256)
void proj(const float* __restrict__ hbuf, const float* __restrict__ Wp,
          const float* __restrict__ bp, float* __restrict__ out) {
    const int o    = blockIdx.x * 4 + (threadIdx.x >> 6);
    const int lane = threadIdx.x & 63;
    const int b = o >> 11, p = o & 2047;
    const float* hv = hbuf + (size_t)b * D_DIM;
    const float* wp = Wp   + (size_t)p * D_DIM;
    float s = 0.0f;
    for (int e = lane; e < D_DIM; e += 64)
        s += hv[e] * wp[e];
    #pragma unroll
    for (int off = 32; off; off >>= 1) s += __shfl_down(s, off);
    if (lane == 0) out[o] = s + bp[p];
}

// ---------------- launch ---------------------------------------------------

extern "C" void kernel_launch(void* const* d_in, const int* in_sizes, int n_in,
                              void* d_out, int out_size, void* d_ws, size_t ws_size,
                              hipStream_t stream) {
    const float* x   = (const float*)d_in[0];
    const float* h   = (const float*)d_in[1];
    const float* Wi  = (const float*)d_in[2];  const float* bWi = (const float*)d_in[3];
    const float* Ui  = (const float*)d_in[4];  const float* bUi = (const float*)d_in[5];
    // Wf/bWf/Uf/bUf (6..9) are dead: f-gate multiplies a zero cell state
    const float* Wc  = (const float*)d_in[10]; const float* bWc = (const float*)d_in[11];
    const float* Uc  = (const float*)d_in[12]; const float* bUc = (const float*)d_in[13];
    const float* Wo  = (const float*)d_in[14]; const float* bWo = (const float*)d_in[15];
    const float* Uo  = (const float*)d_in[16]; const float* bUo = (const float*)d_in[17];
    const float* Wp  = (const float*)d_in[18]; const float* bp  = (const float*)d_in[19];

    float* out = (float*)d_out;               // [0,8192) hidden_state, then c
    char*  ws  = (char*)d_ws;

    __hip_bfloat16* Abf  = (__hip_bfloat16*)ws;                          // 64 MiB
    __hip_bfloat16* Bpk  = (__hip_bfloat16*)(ws + ((size_t)64 << 20));   // 32 MiB
    float*          hbuf = (float*)(ws + ((size_t)96 << 20));            // 32 KiB

    // 1) convert/pack to bf16
    pack2<<<16384, 256, 0, stream>>>(x, h, Abf, M_TOT * KTOT / 8);
    pack_gates<<<8192, 256, 0, stream>>>(Wi, Ui, Wc, Uc, Bpk);

    // 2) fused dual-gate 8-phase GEMM -> c
    gemm8<<<(M_TOT / 256) * (NPACK / 256), 512, 0, stream>>>(
        Abf, Bpk, bWi, bUi, bWc, bUc, out + 8192);

    // 3) last-timestep o-gate (reads c from out), then 4) projection
    last_gate<<<2048, 256, 0, stream>>>(x, h, Wo, bWo, Uo, bUo, out + 8192,
                                        (float*)hbuf);
    proj<<<2048, 256, 0, stream>>>(hbuf, Wp, bp, out);
}

// Round 6
// 333.236 us; speedup vs baseline: 1.0686x; 1.0686x over previous
//
#include <hip/hip_runtime.h>
#include <hip/hip_bf16.h>

typedef short short8 __attribute__((ext_vector_type(8)));
typedef unsigned short ushort8v __attribute__((ext_vector_type(8)));
typedef float f32x4 __attribute__((ext_vector_type(4)));

#define D_DIM 2048
#define KTOT 4096      // x|h concatenated along K
#define M_TOT 8192     // B*S
#define NPACK 4096     // interleaved Bi|Bc rows

// ---------------- helpers ----------------

__device__ __forceinline__ unsigned short f2bf(float f) {
    union { float f; unsigned u; } c; c.f = f;
    unsigned u = c.u;
    u += 0x7fffu + ((u >> 16) & 1u);   // round-to-nearest-even
    return (unsigned short)(u >> 16);
}

__device__ __forceinline__ float fast_tanh(float x) {
    float ax = fabsf(x);
    float ez = __expf(2.0f * fminf(ax, 15.0f));
    float t = (ez - 1.0f) / (ez + 1.0f);
    return copysignf(t, x);
}

#define GLOAD_LDS16(g, l)                                                     \
    __builtin_amdgcn_global_load_lds(                                         \
        (const __attribute__((address_space(1))) void*)(g),                   \
        (__attribute__((address_space(3))) void*)(l), 16, 0, 0)

#define WAITVM_(N) asm volatile("s_waitcnt vmcnt(" #N ")" ::: "memory")
#define WAITVM(N)  WAITVM_(N)
#define WAITLG_(N) asm volatile("s_waitcnt lgkmcnt(" #N ")" ::: "memory")
#define WAITLG(N)  WAITLG_(N)

// ---------------- pack two f32 [R][2048] matrices into bf16 [R][4096] ------

__global__ __launch_bounds__(256)
void pack2(const float* __restrict__ X, const float* __restrict__ H,
           __hip_bfloat16* __restrict__ dst, int total8) {
    int t = blockIdx.x * 256 + threadIdx.x;
    if (t >= total8) return;
    long e0 = (long)t * 8;
    long r  = e0 >> 12;            // / 4096
    int  k  = (int)(e0 & 4095);
    const float* src = (k < D_DIM) ? (X + r * D_DIM + k)
                                   : (H + r * D_DIM + (k - D_DIM));
    float4 v0 = *(const float4*)(src);
    float4 v1 = *(const float4*)(src + 4);
    ushort8v o;
    o[0] = f2bf(v0.x); o[1] = f2bf(v0.y); o[2] = f2bf(v0.z); o[3] = f2bf(v0.w);
    o[4] = f2bf(v1.x); o[5] = f2bf(v1.y); o[6] = f2bf(v1.z); o[7] = f2bf(v1.w);
    *(ushort8v*)(dst + e0) = o;
}

// ---- pack gate weights, Bi/Bc interleaved in 16-row groups ----------------

__global__ __launch_bounds__(256)
void pack_gates(const float* __restrict__ Wi, const float* __restrict__ Ui,
                const float* __restrict__ Wc, const float* __restrict__ Uc,
                __hip_bfloat16* __restrict__ dst) {
    int t = blockIdx.x * 256 + threadIdx.x;    // 4096*512 threads
    const int g = t >> 9;
    const int k = (t & 511) * 8;
    const int w = g & 31;
    const int n = ((g >> 5) << 4) | (w & 15);
    const float* Wm = (w & 16) ? Wc : Wi;
    const float* Um = (w & 16) ? Uc : Ui;
    const float* src = (k < D_DIM) ? (Wm + (size_t)n * D_DIM + k)
                                   : (Um + (size_t)n * D_DIM + (k - D_DIM));
    float4 v0 = *(const float4*)(src);
    float4 v1 = *(const float4*)(src + 4);
    ushort8v o;
    o[0] = f2bf(v0.x); o[1] = f2bf(v0.y); o[2] = f2bf(v0.z); o[3] = f2bf(v0.w);
    o[4] = f2bf(v1.x); o[5] = f2bf(v1.y); o[6] = f2bf(v1.z); o[7] = f2bf(v1.w);
    *(ushort8v*)(dst + (size_t)g * KTOT + k) = o;
}

// ---------------- 8-phase 256x256 fused GEMM, deep-prefetch ----------------
// Register fragments prefetched one phase ahead (lgkm 4/8 ledger, round 4).
// Staging: ONE half-tile per phase, targeting the slot freed two phases
// earlier: P1: A.kh1(t+1)  P2: B.kh1(t+1)  P3: A.kh0(t+2)  P4: B.kh0(t+2).
// vmcnt(6) at P1 and P3 ONLY, placed BEFORE the barrier so completion is
// published to all waves before the staged half is ds_read next phase.
// Issue-to-confirm slack = 3-4 phases (~4000 cyc >> HBM latency).

#define BK 64
#define NT (KTOT / BK)   // 64 K-tiles

__device__ __forceinline__ void mfma16(f32x4 (&acc)[8][4], int mb,
                                       const short8 (&a)[4], const short8 (&b)[4]) {
    #pragma unroll
    for (int m = 0; m < 4; ++m)
        #pragma unroll
        for (int n = 0; n < 4; ++n)
            acc[mb + m][n] = __builtin_amdgcn_mfma_f32_16x16x32_bf16(
                a[m], b[n], acc[mb + m][n], 0, 0, 0);
}

// 4 ds_read_b128 from per-thread base + compile-time immediate
#define READ4(dst, base, IMM)                                                 \
    { _Pragma("unroll")                                                       \
      for (int m_ = 0; m_ < 4; ++m_)                                          \
          dst[m_] = *(const short8*)((base) + (IMM) + m_ * 1024); }

// stage one 256x32 half-tile: 2 global_load_lds per thread
#define STAGE_A(DIMM, KB)                                                     \
    { GLOAD_LDS16(gA0 + (KB), ldsA + (DIMM) + dOff);                          \
      GLOAD_LDS16(gA1 + (KB), ldsA + (DIMM) + dOff + 1024); }
#define STAGE_B(DIMM, KB)                                                     \
    { GLOAD_LDS16(gB0 + (KB), ldsB + (DIMM) + dOff);                          \
      GLOAD_LDS16(gB1 + (KB), ldsB + (DIMM) + dOff + 1024); }

// one K-tile: 4 phases. CUR/NXT in {0,32768} compile-time.
#define TILE(CUR, NXT, V1, V3, ST12, ST34, PF4)                               \
  {                                                                           \
    /* P1: MFMA aP,bP (kh0 m0-3); read aQ; stage A.kh1(t+1) */                \
    READ4(aQ, rdA, (CUR) + 4096);                                             \
    if (ST12) STAGE_A((NXT) + 16384, kb + 64);                                \
    WAITVM(V1);                                                               \
    __builtin_amdgcn_s_barrier();                                             \
    WAITLG(4);                                                                \
    __builtin_amdgcn_sched_barrier(0);                                        \
    __builtin_amdgcn_s_setprio(1); mfma16(acc, 0, aP, bP);                    \
    __builtin_amdgcn_s_setprio(0);                                            \
    /* P2: MFMA aQ,bP (kh0 m4-7); read aP,bQ (kh1); stage B.kh1(t+1) */       \
    READ4(aP, rdA, (CUR) + 16384);                                            \
    READ4(bQ, rdB, (CUR) + 16384);                                            \
    if (ST12) STAGE_B((NXT) + 16384, kb + 64);                                \
    __builtin_amdgcn_s_barrier();                                             \
    WAITLG(8);                                                                \
    __builtin_amdgcn_sched_barrier(0);                                        \
    __builtin_amdgcn_s_setprio(1); mfma16(acc, 4, aQ, bP);                    \
    __builtin_amdgcn_s_setprio(0);                                            \
    /* P3: MFMA aP,bQ (kh1 m0-3); read aQ; stage A.kh0(t+2) */                \
    READ4(aQ, rdA, (CUR) + 16384 + 4096);                                     \
    if (ST34) STAGE_A((CUR), kb + 128);                                       \
    WAITVM(V3);                                                               \
    __builtin_amdgcn_s_barrier();                                             \
    WAITLG(4);                                                                \
    __builtin_amdgcn_sched_barrier(0);                                        \
    __builtin_amdgcn_s_setprio(1); mfma16(acc, 0, aP, bQ);                    \
    __builtin_amdgcn_s_setprio(0);                                            \
    /* P4: MFMA aQ,bQ (kh1 m4-7); read aP,bP (next kh0); stage B.kh0(t+2) */  \
    if (PF4) { READ4(aP, rdA, (NXT)); READ4(bP, rdB, (NXT)); }                \
    if (ST34) STAGE_B((CUR), kb + 128);                                       \
    __builtin_amdgcn_s_barrier();                                             \
    if (PF4) { WAITLG(8); } else { WAITLG(0); }                               \
    __builtin_amdgcn_sched_barrier(0);                                        \
    __builtin_amdgcn_s_setprio(1); mfma16(acc, 4, aQ, bQ);                    \
    __builtin_amdgcn_s_setprio(0);                                            \
  }

__global__ __launch_bounds__(512, 2)
void gemm8(const __hip_bfloat16* __restrict__ A,
           const __hip_bfloat16* __restrict__ Bp,
           const float* __restrict__ bWi, const float* __restrict__ bUi,
           const float* __restrict__ bWc, const float* __restrict__ bUc,
           float* __restrict__ Cout) {
    // [buf][khalf][row][32 cols]; buf stride 32768 B, khalf stride 16384 B
    __shared__ __hip_bfloat16 sA[2][2][256][32];
    __shared__ __hip_bfloat16 sB[2][2][256][32];

    const int tid  = threadIdx.x;
    const int wid  = tid >> 6;
    const int lane = tid & 63;

    // XCD swizzle: 512 blocks, 512%8==0 -> bijective
    int bid = blockIdx.x;
    bid = (bid & 7) * 64 + (bid >> 3);
    const int tn = (bid & 15) * 256;   // Bpack row tile (16 tiles)
    const int tm = (bid >> 4) * 256;   // M tile (32 tiles)

    const int wr  = (wid >> 2) * 128;  // wave M offset
    const int wc  = (wid & 3) * 64;    // wave Bpack-row offset
    const int r15 = lane & 15;
    // balanced-quad swizzle: unit p = g ^ ((row>>1)&3); conflict-free b128
    const int uswz16 = (((lane >> 4) ^ ((r15 >> 1) & 3)) * 16);

    // ---- hoisted staging addresses (computed once) ----
    const int Lb0  = wid * 128 + lane;            // 16B-unit index, j=0
    const int row0 = Lb0 >> 2;
    const int u0   = (Lb0 & 3) ^ ((Lb0 >> 3) & 3);   // j=1 swizzle identical
    const char* gA0 = (const char*)(A  + (size_t)(tm + row0) * KTOT) + u0 * 16;
    const char* gA1 = gA0 + (size_t)16 * KTOT * 2;   // j=1 = rows +16
    const char* gB0 = (const char*)(Bp + (size_t)(tn + row0) * KTOT) + u0 * 16;
    const char* gB1 = gB0 + (size_t)16 * KTOT * 2;
    char* ldsA = (char*)sA;
    char* ldsB = (char*)sB;
    const int dOff = Lb0 * 16;                    // LDS dest byte, j=0

    // ---- hoisted ds_read bases ----
    const char* rdA = (const char*)sA + (wr + r15) * 64 + uswz16;
    const char* rdB = (const char*)sB + (wc + r15) * 64 + uswz16;

    f32x4 acc[8][4] = {};
    short8 aP[4], aQ[4], bP[4], bQ[4];

    // ---- prologue: stage kh0(0), kh1(0), kh0(1); confirm kh0(0); read P1 --
    STAGE_A(0, 0);        STAGE_B(0, 0);         // kh0(0)
    STAGE_A(16384, 64);   STAGE_B(16384, 64);    // kh1(0)
    STAGE_A(32768, 128);  STAGE_B(32768, 128);   // kh0(1)
    WAITVM(8);                                   // oldest 4 (kh0(0)) landed
    __builtin_amdgcn_s_barrier();
    READ4(aP, rdA, 0);
    READ4(bP, rdB, 0);

    int kb = 128;   // byte offset of tile (t+1)'s kh0 column
    #pragma unroll 1
    for (int it = 0; it < 31; ++it) {
        TILE(0, 32768, 6, 6, 1, 1, 1); kb += 128;   // even tile
        TILE(32768, 0, 6, 6, 1, 1, 1); kb += 128;   // odd tile
    }
    TILE(0, 32768, 6, 4, 1, 0, 1); kb += 128;       // t = 62 (no kh0(64))
    TILE(32768, 0, 0, 0, 0, 0, 0);                  // t = 63 (full drain)

    // ---- epilogue: pair (Zi,Zc) fragments -> c = exp(Zi)*tanh(Zc) ----
    const int rg4 = (lane >> 4) * 4;
    #pragma unroll
    for (int q = 0; q < 2; ++q) {
        const int gn = (tn >> 1) + (wc >> 1) + q * 16 + r15;
        const float bi_ = bWi[gn] + bUi[gn];
        const float bc_ = bWc[gn] + bUc[gn];
        #pragma unroll
        for (int m = 0; m < 8; ++m) {
            const int gm = tm + wr + m * 16 + rg4;
            #pragma unroll
            for (int r = 0; r < 4; ++r) {
                const float zi = acc[m][2 * q][r]     + bi_;
                const float zc = acc[m][2 * q + 1][r] + bc_;
                Cout[(size_t)(gm + r) * D_DIM + gn] = __expf(zi) * fast_tanh(zc);
            }
        }
    }
}

// ---------------- last-timestep o-gate: hbuf[b][e] = sig(Zo)*tanh(c) -------

__global__ __launch_bounds__(256)
void last_gate(const float* __restrict__ x, const float* __restrict__ h,
               const float* __restrict__ Wo, const float* __restrict__ bWo,
               const float* __restrict__ Uo, const float* __restrict__ bUo,
               const float* __restrict__ cfull, float* __restrict__ hbuf) {
    const int o    = blockIdx.x * 4 + (threadIdx.x >> 6);
    const int lane = threadIdx.x & 63;
    const int b = o >> 11, e = o & 2047;
    const float* xr = x  + ((size_t)b * D_DIM + (D_DIM - 1)) * D_DIM;
    const float* hr = h  + ((size_t)b * D_DIM + (D_DIM - 1)) * D_DIM;
    const float* wo = Wo + (size_t)e * D_DIM;
    const float* uo = Uo + (size_t)e * D_DIM;
    float s = 0.0f;
    for (int d = lane; d < D_DIM; d += 64)
        s += xr[d] * wo[d] + hr[d] * uo[d];
    #pragma unroll
    for (int off = 32; off; off >>= 1) s += __shfl_down(s, off);
    if (lane == 0) {
        const float zo  = s + bWo[e] + bUo[e];
        const float sig = 1.0f / (1.0f + __expf(-zo));
        const float cv  = cfull[((size_t)b * D_DIM + (D_DIM - 1)) * D_DIM + e];
        hbuf[o] = sig * fast_tanh(cv);
    }
}

// ---------------- final projection: out[b][p] = hbuf[b] . Wp[p] + bp[p] ----

__global__ __launch_bounds__(256)
void proj(const float* __restrict__ hbuf, const float* __restrict__ Wp,
          const float* __restrict__ bp, float* __restrict__ out) {
    const int o    = blockIdx.x * 4 + (threadIdx.x >> 6);
    const int lane = threadIdx.x & 63;
    const int b = o >> 11, p = o & 2047;
    const float* hv = hbuf + (size_t)b * D_DIM;
    const float* wp = Wp   + (size_t)p * D_DIM;
    float s = 0.0f;
    for (int e = lane; e < D_DIM; e += 64)
        s += hv[e] * wp[e];
    #pragma unroll
    for (int off = 32; off; off >>= 1) s += __shfl_down(s, off);
    if (lane == 0) out[o] = s + bp[p];
}

// ---------------- launch ---------------------------------------------------

extern "C" void kernel_launch(void* const* d_in, const int* in_sizes, int n_in,
                              void* d_out, int out_size, void* d_ws, size_t ws_size,
                              hipStream_t stream) {
    const float* x   = (const float*)d_in[0];
    const float* h   = (const float*)d_in[1];
    const float* Wi  = (const float*)d_in[2];  const float* bWi = (const float*)d_in[3];
    const float* Ui  = (const float*)d_in[4];  const float* bUi = (const float*)d_in[5];
    // Wf/bWf/Uf/bUf (6..9) are dead: f-gate multiplies a zero cell state
    const float* Wc  = (const float*)d_in[10]; const float* bWc = (const float*)d_in[11];
    const float* Uc  = (const float*)d_in[12]; const float* bUc = (const float*)d_in[13];
    const float* Wo  = (const float*)d_in[14]; const float* bWo = (const float*)d_in[15];
    const float* Uo  = (const float*)d_in[16]; const float* bUo = (const float*)d_in[17];
    const float* Wp  = (const float*)d_in[18]; const float* bp  = (const float*)d_in[19];

    float* out = (float*)d_out;               // [0,8192) hidden_state, then c
    char*  ws  = (char*)d_ws;

    __hip_bfloat16* Abf  = (__hip_bfloat16*)ws;                          // 64 MiB
    __hip_bfloat16* Bpk  = (__hip_bfloat16*)(ws + ((size_t)64 << 20));   // 32 MiB
    float*          hbuf = (float*)(ws + ((size_t)96 << 20));            // 32 KiB

    // 1) convert/pack to bf16
    pack2<<<16384, 256, 0, stream>>>(x, h, Abf, M_TOT * KTOT / 8);
    pack_gates<<<8192, 256, 0, stream>>>(Wi, Ui, Wc, Uc, Bpk);

    // 2) fused dual-gate 8-phase GEMM -> c
    gemm8<<<(M_TOT / 256) * (NPACK / 256), 512, 0, stream>>>(
        Abf, Bpk, bWi, bUi, bWc, bUc, out + 8192);

    // 3) last-timestep o-gate (reads c from out), then 4) projection
    last_gate<<<2048, 256, 0, stream>>>(x, h, Wo, bWo, Uo, bUo, out + 8192,
                                        (float*)hbuf);
    proj<<<2048, 256, 0, stream>>>(hbuf, Wp, bp, out);
}

// Round 7
// 319.973 us; speedup vs baseline: 1.1129x; 1.0414x over previous
//
#include <hip/hip_runtime.h>
#include <hip/hip_bf16.h>

typedef short short8 __attribute__((ext_vector_type(8)));
typedef unsigned short ushort8v __attribute__((ext_vector_type(8)));
typedef float f32x4 __attribute__((ext_vector_type(4)));

#define D_DIM 2048
#define KTOT 4096      // x|h concatenated along K
#define M_TOT 8192     // B*S
#define NPACK 4096     // interleaved Bi|Bc rows

// ---------------- helpers ----------------

__device__ __forceinline__ unsigned short f2bf(float f) {
    union { float f; unsigned u; } c; c.f = f;
    unsigned u = c.u;
    u += 0x7fffu + ((u >> 16) & 1u);   // round-to-nearest-even
    return (unsigned short)(u >> 16);
}

__device__ __forceinline__ float fast_tanh(float x) {
    float ax = fabsf(x);
    float ez = __expf(2.0f * fminf(ax, 15.0f));
    float t = (ez - 1.0f) / (ez + 1.0f);
    return copysignf(t, x);
}

#define GLOAD_LDS16(g, l)                                                     \
    __builtin_amdgcn_global_load_lds(                                         \
        (const __attribute__((address_space(1))) void*)(g),                   \
        (__attribute__((address_space(3))) void*)(l), 16, 0, 0)

#define WAITVM_(N) asm volatile("s_waitcnt vmcnt(" #N ")" ::: "memory")
#define WAITVM(N)  WAITVM_(N)
#define WAITLG0    asm volatile("s_waitcnt lgkmcnt(0)" ::: "memory")
#define BAR        __builtin_amdgcn_s_barrier()
#define SCHB       __builtin_amdgcn_sched_barrier(0)
#define PRIO1      __builtin_amdgcn_s_setprio(1)
#define PRIO0      __builtin_amdgcn_s_setprio(0)

// ---------------- pack two f32 [R][2048] matrices into bf16 [R][4096] ------

__global__ __launch_bounds__(256)
void pack2(const float* __restrict__ X, const float* __restrict__ H,
           __hip_bfloat16* __restrict__ dst, int total8) {
    int t = blockIdx.x * 256 + threadIdx.x;
    if (t >= total8) return;
    long e0 = (long)t * 8;
    long r  = e0 >> 12;            // / 4096
    int  k  = (int)(e0 & 4095);
    const float* src = (k < D_DIM) ? (X + r * D_DIM + k)
                                   : (H + r * D_DIM + (k - D_DIM));
    float4 v0 = *(const float4*)(src);
    float4 v1 = *(const float4*)(src + 4);
    ushort8v o;
    o[0] = f2bf(v0.x); o[1] = f2bf(v0.y); o[2] = f2bf(v0.z); o[3] = f2bf(v0.w);
    o[4] = f2bf(v1.x); o[5] = f2bf(v1.y); o[6] = f2bf(v1.z); o[7] = f2bf(v1.w);
    *(ushort8v*)(dst + e0) = o;
}

// ---- pack gate weights, Bi/Bc interleaved in 16-row groups ----------------

__global__ __launch_bounds__(256)
void pack_gates(const float* __restrict__ Wi, const float* __restrict__ Ui,
                const float* __restrict__ Wc, const float* __restrict__ Uc,
                __hip_bfloat16* __restrict__ dst) {
    int t = blockIdx.x * 256 + threadIdx.x;    // 4096*512 threads
    const int g = t >> 9;
    const int k = (t & 511) * 8;
    const int w = g & 31;
    const int n = ((g >> 5) << 4) | (w & 15);
    const float* Wm = (w & 16) ? Wc : Wi;
    const float* Um = (w & 16) ? Uc : Ui;
    const float* src = (k < D_DIM) ? (Wm + (size_t)n * D_DIM + k)
                                   : (Um + (size_t)n * D_DIM + (k - D_DIM));
    float4 v0 = *(const float4*)(src);
    float4 v1 = *(const float4*)(src + 4);
    ushort8v o;
    o[0] = f2bf(v0.x); o[1] = f2bf(v0.y); o[2] = f2bf(v0.z); o[3] = f2bf(v0.w);
    o[4] = f2bf(v1.x); o[5] = f2bf(v1.y); o[6] = f2bf(v1.z); o[7] = f2bf(v1.w);
    *(ushort8v*)(dst + (size_t)g * KTOT + k) = o;
}

// ---------------- m201-template 256x256 fused GEMM -------------------------
// 8 phases / 2 K-tiles. Per phase: {same-phase ds_reads, 1 half-tile stage,
// bar, lgkmcnt(0), setprio, 16 MFMA (one acc QUADRANT 4m x 2n x 2k), setprio,
// bar}. Quadrant rotation => consecutive phases hit disjoint accumulators.
// Staging: row-halves (128 rows x 64 cols); schedule (iter i, t0=2i, t1=2i+1):
//   ph1:A1h0(t1) ph2:A1h1(t1) ph3:B0h0(t0+2) ph4:B0h1(t0+2)+vmcnt(4)
//   ph5:A0h0(t0+2) ph6:A0h1(t0+2) ph7:B1h0(t1+2) ph8:B1h1(t1+2)+vmcnt(4)
// vmcnt(4) confirms exactly the 4 halves the next K-tile reads (ledger
// traced for prologue / steady state / tail).
// LDS swizzle (rows = 64 bf16 = 8 x 16B slots): slot = (kh^row2)*4 + (g^row10)
// -> 8 lanes per bank-quad on every wave64 ds_read_b128 (conflict-free);
// write side stays linear for global_load_lds; source pre-swizzled.

__device__ __forceinline__ f32x4 mf(short8 a, short8 b, f32x4 c) {
    return __builtin_amdgcn_mfma_f32_16x16x32_bf16(a, b, c, 0, 0, 0);
}

#define RD4A(BUF, IMM)                                                        \
  { _Pragma("unroll") for (int m_ = 0; m_ < 4; ++m_) {                        \
      ak0[m_] = *(const short8*)(rdA0 + (BUF) + (IMM) + m_ * 2048);           \
      ak1[m_] = *(const short8*)(rdA1 + (BUF) + (IMM) + m_ * 2048); } }

#define RDB(d0, d1, BUF, IMM)                                                 \
  { _Pragma("unroll") for (int n_ = 0; n_ < 2; ++n_) {                        \
      d0[n_] = *(const short8*)(rdB0 + (BUF) + (IMM) + n_ * 2048);            \
      d1[n_] = *(const short8*)(rdB1 + (BUF) + (IMM) + n_ * 2048); } }

#define MF16(MB, NB, bk0, bk1)                                                \
  { _Pragma("unroll") for (int m_ = 0; m_ < 4; ++m_)                          \
    _Pragma("unroll") for (int n_ = 0; n_ < 2; ++n_) {                        \
      acc[(MB)+m_][(NB)+n_] = mf(ak0[m_], bk0[n_], acc[(MB)+m_][(NB)+n_]);    \
      acc[(MB)+m_][(NB)+n_] = mf(ak1[m_], bk1[n_], acc[(MB)+m_][(NB)+n_]); } }

// stage one 128-row half-tile (2 x global_load_lds / thread)
#define SA0(BUFB, KB) { GLOAD_LDS16(gAh0 + (KB), ldsA + (BUFB) + dOff);       \
                        GLOAD_LDS16(gAh0 + (KB) + 524288, ldsA + (BUFB) + dOff + 8192); }
#define SA1(BUFB, KB) { GLOAD_LDS16(gAh1 + (KB), ldsA + (BUFB) + 16384 + dOff); \
                        GLOAD_LDS16(gAh1 + (KB) + 524288, ldsA + (BUFB) + 16384 + dOff + 8192); }
#define SB0(BUFB, KB) { GLOAD_LDS16(gBh0 + (KB), ldsB + (BUFB) + dOff);       \
                        GLOAD_LDS16(gBh0 + (KB) + 524288, ldsB + (BUFB) + dOff + 8192); }
#define SB1(BUFB, KB) { GLOAD_LDS16(gBh1 + (KB), ldsB + (BUFB) + 16384 + dOff); \
                        GLOAD_LDS16(gBh1 + (KB) + 524288, ldsB + (BUFB) + 16384 + dOff + 8192); }

// one K-tile = 4 phases; BUF in {0, 32768} compile-time
#define KTILE(BUF, S1, S2, S3, S4, VMN)                                       \
  { /* ph1: A own-half m0-3 + B n0-1 (12 reads); MFMA m0-3 x n0-1 */          \
    RD4A(BUF, 0);                                                             \
    RDB(b01k0, b01k1, BUF, 0);                                                \
    S1;                                                                       \
    BAR; WAITLG0; SCHB;                                                       \
    PRIO1; MF16(0, 0, b01k0, b01k1); PRIO0; BAR;                              \
    /* ph2: B n2-3 (4 reads); MFMA m0-3 x n2-3 */                             \
    RDB(b23k0, b23k1, BUF, 4096);                                             \
    S2;                                                                       \
    BAR; WAITLG0; SCHB;                                                       \
    PRIO1; MF16(0, 2, b23k0, b23k1); PRIO0; BAR;                              \
    /* ph3: A m4-7 (8 reads); MFMA m4-7 x n0-1 */                             \
    RD4A(BUF, 8192);                                                          \
    S3;                                                                       \
    BAR; WAITLG0; SCHB;                                                       \
    PRIO1; MF16(4, 0, b01k0, b01k1); PRIO0; BAR;                              \
    /* ph4: no reads; stage + vmcnt; MFMA m4-7 x n2-3 */                      \
    S4; VMN;                                                                  \
    BAR; SCHB;                                                                \
    PRIO1; MF16(4, 2, b23k0, b23k1); PRIO0; BAR;                              \
  }

#define NOSTG (void)0

__global__ __launch_bounds__(512, 2)
void gemm8(const __hip_bfloat16* __restrict__ A,
           const __hip_bfloat16* __restrict__ Bp,
           const float* __restrict__ bWi, const float* __restrict__ bUi,
           const float* __restrict__ bWc, const float* __restrict__ bUc,
           float* __restrict__ Cout) {
    // [buf][rowhalf][128 rows][64 cols]; buf stride 32768 B, half 16384 B
    __shared__ __hip_bfloat16 sA[2][2][128][64];
    __shared__ __hip_bfloat16 sB[2][2][128][64];

    const int tid  = threadIdx.x;
    const int wid  = tid >> 6;
    const int lane = tid & 63;

    // XCD swizzle: 512 blocks, 512%8==0 -> bijective
    int bid = blockIdx.x;
    bid = (bid & 7) * 64 + (bid >> 3);
    const int tn = (bid & 15) * 256;   // Bpack row tile (16 tiles)
    const int tm = (bid >> 4) * 256;   // M tile (32 tiles)

    const int wr  = (wid >> 2) * 128;  // wave M offset (half = wr>>7)
    const int wc  = (wid & 3) * 64;    // wave Bpack-row offset
    const int r15 = lane & 15;
    const int g   = lane >> 4;

    // read-side swizzled slot bytes (kh=0 / kh=1)
    const int sb    = g ^ (r15 & 3);
    const int khb   = (r15 >> 2) & 1;
    const int slot0 = (khb * 4 + sb) * 16;
    const int slot1 = (((1 ^ khb) * 4) + sb) * 16;

    const char* rdA0 = (const char*)sA + (wr >> 7) * 16384 + r15 * 128 + slot0;
    const char* rdA1 = (const char*)sA + (wr >> 7) * 16384 + r15 * 128 + slot1;
    const char* rdB0 = (const char*)sB + (wc >> 7) * 16384 + (wc & 64) * 128 + r15 * 128 + slot0;
    const char* rdB1 = (const char*)sB + (wc >> 7) * 16384 + (wc & 64) * 128 + r15 * 128 + slot1;

    // ---- hoisted staging addresses ----
    // thread T covers LDS unit T (row r0=T>>3, slot s0=T&7); source col is
    // the logical (kh,g) stored at that slot: kh=(s0>>2)^r0_2, g=(s0&3)^r0_10
    const int r0 = tid >> 3, s0 = tid & 7;
    const int colb = (((s0 >> 2) ^ ((r0 >> 2) & 1)) * 64) +
                     (((s0 & 3) ^ (r0 & 3)) * 16);
    const char* gAh0 = (const char*)(A  + (size_t)(tm + r0) * KTOT) + colb;
    const char* gAh1 = gAh0 + (size_t)128 * KTOT * 2;
    const char* gBh0 = (const char*)(Bp + (size_t)(tn + r0) * KTOT) + colb;
    const char* gBh1 = gBh0 + (size_t)128 * KTOT * 2;
    char* ldsA = (char*)sA;
    char* ldsB = (char*)sB;
    const int dOff = tid * 16;

    f32x4 acc[8][4] = {};
    short8 ak0[4], ak1[4], b01k0[2], b01k1[2], b23k0[2], b23k1[2];

    // ---- prologue: buf0 = tile 0 (B,A), buf1.B = tile 1; confirm buf0 ----
    SB0(0, 0); SB1(0, 0); SA0(0, 0); SA1(0, 0);
    SB0(32768, 128); SB1(32768, 128);
    WAITVM(4);                          // confirms buf0's 4 halves
    BAR;

    int kb = 0;     // t0 byte column = i*256
    #pragma unroll 1
    for (int i = 0; i < 31; ++i) {
        KTILE(0,
              SA0(32768, kb + 128), SA1(32768, kb + 128),
              SB0(0, kb + 256),     SB1(0, kb + 256),
              WAITVM(4));
        KTILE(32768,
              SA0(0, kb + 256),     SA1(0, kb + 256),
              SB0(32768, kb + 384), SB1(32768, kb + 384),
              WAITVM(4));
        kb += 256;
    }
    // i = 31: t0=62, t1=63; only buf1.A(63) still needs staging
    KTILE(0, SA0(32768, kb + 128), SA1(32768, kb + 128),
          NOSTG, NOSTG, WAITVM(0));
    KTILE(32768, NOSTG, NOSTG, NOSTG, NOSTG, NOSTG);

    // ---- epilogue: pair (Zi,Zc) fragments -> c = exp(Zi)*tanh(Zc) ----
    const int rg4 = (lane >> 4) * 4;
    #pragma unroll
    for (int q = 0; q < 2; ++q) {
        const int gn = (tn >> 1) + (wc >> 1) + q * 16 + r15;
        const float bi_ = bWi[gn] + bUi[gn];
        const float bc_ = bWc[gn] + bUc[gn];
        #pragma unroll
        for (int m = 0; m < 8; ++m) {
            const int gm = tm + wr + m * 16 + rg4;
            #pragma unroll
            for (int r = 0; r < 4; ++r) {
                const float zi = acc[m][2 * q][r]     + bi_;
                const float zc = acc[m][2 * q + 1][r] + bc_;
                Cout[(size_t)(gm + r) * D_DIM + gn] = __expf(zi) * fast_tanh(zc);
            }
        }
    }
}

// ---------------- last-timestep o-gate: hbuf[b][e] = sig(Zo)*tanh(c) -------

__global__ __launch_bounds__(256)
void last_gate(const float* __restrict__ x, const float* __restrict__ h,
               const float* __restrict__ Wo, const float* __restrict__ bWo,
               const float* __restrict__ Uo, const float* __restrict__ bUo,
               const float* __restrict__ cfull, float* __restrict__ hbuf) {
    const int o    = blockIdx.x * 4 + (threadIdx.x >> 6);
    const int lane = threadIdx.x & 63;
    const int b = o >> 11, e = o & 2047;
    const float* xr = x  + ((size_t)b * D_DIM + (D_DIM - 1)) * D_DIM;
    const float* hr = h  + ((size_t)b * D_DIM + (D_DIM - 1)) * D_DIM;
    const float* wo = Wo + (size_t)e * D_DIM;
    const float* uo = Uo + (size_t)e * D_DIM;
    float s = 0.0f;
    for (int d = lane; d < D_DIM; d += 64)
        s += xr[d] * wo[d] + hr[d] * uo[d];
    #pragma unroll
    for (int off = 32; off; off >>= 1) s += __shfl_down(s, off);
    if (lane == 0) {
        const float zo  = s + bWo[e] + bUo[e];
        const float sig = 1.0f / (1.0f + __expf(-zo));
        const float cv  = cfull[((size_t)b * D_DIM + (D_DIM - 1)) * D_DIM + e];
        hbuf[o] = sig * fast_tanh(cv);
    }
}

// ---------------- final projection: out[b][p] = hbuf[b] . Wp[p] + bp[p] ----

__global__ __launch_bounds__(256)
void proj(const float* __restrict__ hbuf, const float* __restrict__ Wp,
          const float* __restrict__ bp, float* __restrict__ out) {
    const int o    = blockIdx.x * 4 + (threadIdx.x >> 6);
    const int lane = threadIdx.x & 63;
    const int b = o >> 11, p = o & 2047;
    const float* hv = hbuf + (size_t)b * D_DIM;
    const float* wp = Wp   + (size_t)p * D_DIM;
    float s = 0.0f;
    for (int e = lane; e < D_DIM; e += 64)
        s += hv[e] * wp[e];
    #pragma unroll
    for (int off = 32; off; off >>= 1) s += __shfl_down(s, off);
    if (lane == 0) out[o] = s + bp[p];
}

// ---------------- launch ---------------------------------------------------

extern "C" void kernel_launch(void* const* d_in, const int* in_sizes, int n_in,
                              void* d_out, int out_size, void* d_ws, size_t ws_size,
                              hipStream_t stream) {
    const float* x   = (const float*)d_in[0];
    const float* h   = (const float*)d_in[1];
    const float* Wi  = (const float*)d_in[2];  const float* bWi = (const float*)d_in[3];
    const float* Ui  = (const float*)d_in[4];  const float* bUi = (const float*)d_in[5];
    // Wf/bWf/Uf/bUf (6..9) are dead: f-gate multiplies a zero cell state
    const float* Wc  = (const float*)d_in[10]; const float* bWc = (const float*)d_in[11];
    const float* Uc  = (const float*)d_in[12]; const float* bUc = (const float*)d_in[13];
    const float* Wo  = (const float*)d_in[14]; const float* bWo = (const float*)d_in[15];
    const float* Uo  = (const float*)d_in[16]; const float* bUo = (const float*)d_in[17];
    const float* Wp  = (const float*)d_in[18]; const float* bp  = (const float*)d_in[19];

    float* out = (float*)d_out;               // [0,8192) hidden_state, then c
    char*  ws  = (char*)d_ws;

    __hip_bfloat16* Abf  = (__hip_bfloat16*)ws;                          // 64 MiB
    __hip_bfloat16* Bpk  = (__hip_bfloat16*)(ws + ((size_t)64 << 20));   // 32 MiB
    float*          hbuf = (float*)(ws + ((size_t)96 << 20));            // 32 KiB

    // 1) convert/pack to bf16
    pack2<<<16384, 256, 0, stream>>>(x, h, Abf, M_TOT * KTOT / 8);
    pack_gates<<<8192, 256, 0, stream>>>(Wi, Ui, Wc, Uc, Bpk);

    // 2) fused dual-gate 8-phase GEMM -> c
    gemm8<<<(M_TOT / 256) * (NPACK / 256), 512, 0, stream>>>(
        Abf, Bpk, bWi, bUi, bWc, bUc, out + 8192);

    // 3) last-timestep o-gate (reads c from out), then 4) projection
    last_gate<<<2048, 256, 0, stream>>>(x, h, Wo, bWo, Uo, bUo, out + 8192,
                                        (float*)hbuf);
    proj<<<2048, 256, 0, stream>>>(hbuf, Wp, bp, out);
}